// Round 13
// baseline (170.877 us; speedup 1.0000x reference)
//
#include <hip/hip_runtime.h>
#include <hip/hip_bf16.h>

typedef __bf16 bf16x8 __attribute__((ext_vector_type(8)));
typedef float  f32x4  __attribute__((ext_vector_type(4)));
typedef unsigned short u16x8 __attribute__((ext_vector_type(8)));
typedef unsigned short us4   __attribute__((ext_vector_type(4)));
typedef unsigned int   u32x4 __attribute__((ext_vector_type(4)));

#define HH    8
#define NN    4096
#define FIN   512
#define FOUT  64
#define ALPHA 0.2f

// ---------------------------------------------------------------------------
// k0: W[h][f][o] (fp32) -> WT[h][o][f] (bf16), coalesced via LDS 64x64 tile.
// ---------------------------------------------------------------------------
__global__ __launch_bounds__(256) void k_transpose_w(
    const float* __restrict__ Wsrc, __hip_bfloat16* __restrict__ WT) {
    __shared__ __hip_bfloat16 lt[64][65];
    const int h  = blockIdx.x >> 3;
    const int f0 = (blockIdx.x & 7) * 64;
    const int tid = threadIdx.x;
#pragma unroll
    for (int p = 0; p < 16; ++p) {
        int f = p * 4 + (tid >> 6);
        int o = tid & 63;
        lt[f][o] = __float2bfloat16(Wsrc[((size_t)h * FIN + f0 + f) * FOUT + o]);
    }
    __syncthreads();
#pragma unroll
    for (int p = 0; p < 16; ++p) {
        int o = p * 4 + (tid >> 6);
        int f = tid & 63;
        WT[((size_t)h * FOUT + o) * FIN + f0 + f] = lt[f][o];
    }
}

// ---------------------------------------------------------------------------
// k_prep: FUSED adjacency bit-pack + projection (independent work).
// Blocks [0,2048): in-place pack — block b owns rows 2b,2b+1; first 1 KB of
//   its 32768-B region becomes bits (NOT contiguous across row-pairs).
// Blocks [2048,2304): projection: tile = pb&127 (32 rows), hgroup = pb>>7.
// ---------------------------------------------------------------------------
__global__ __launch_bounds__(256) void k_prep(
    int* __restrict__ adj,
    const float* __restrict__ feat,
    const __hip_bfloat16* __restrict__ WT,
    const float* __restrict__ a_src,
    const float* __restrict__ a_dst,
    unsigned short* __restrict__ WhT,
    float* __restrict__ srcv,
    unsigned short* __restrict__ Ebf, unsigned short* __restrict__ Fbf) {
    __shared__ alignas(16) __hip_bfloat16 lfeat[32][520];

    const int tid = threadIdx.x;

    if (blockIdx.x < 2048) {   // ---- pack path ----
        const size_t base = (size_t)blockIdx.x * 8192;
        unsigned m = 0;
#pragma unroll
        for (int p = 0; p < 8; ++p) {
            int4 v = *(const int4*)(adj + base + tid * 32 + p * 4);
            m |= (unsigned)(v.x > 0) << (p * 4);
            m |= (unsigned)(v.y > 0) << (p * 4 + 1);
            m |= (unsigned)(v.z > 0) << (p * 4 + 2);
            m |= (unsigned)(v.w > 0) << (p * 4 + 3);
        }
        __syncthreads();
        ((unsigned*)adj)[base + tid] = m;
        return;
    }

    // ---- projection path ----
    const int pb   = blockIdx.x - 2048;
    const int tile = pb & 127;            // 32 rows per block
    const int hgy  = pb >> 7;             // 0..1

#pragma unroll
    for (int p = 0; p < 16; ++p) {
        int idx  = p * 256 + tid;
        int row  = idx >> 7;
        int col4 = (idx & 127) * 4;
        float4 f = *(const float4*)(feat + (size_t)(tile * 32 + row) * FIN + col4);
        __hip_bfloat16* dst = &lfeat[row][col4];
        dst[0] = __float2bfloat16(f.x); dst[1] = __float2bfloat16(f.y);
        dst[2] = __float2bfloat16(f.z); dst[3] = __float2bfloat16(f.w);
    }
    __syncthreads();

    const int h     = hgy * 4 + (tid >> 6);
    const int lane  = tid & 63;
    const int row16 = lane & 15;
    const int quad  = lane >> 4;

    const unsigned short* WTu = (const unsigned short*)WT + (size_t)h * FOUT * FIN;

    f32x4 acc[2][4] = {};
    for (int k0 = 0; k0 < FIN; k0 += 32) {
        bf16x8 a0 = *(const bf16x8*)&lfeat[row16][k0 + quad * 8];
        bf16x8 a1 = *(const bf16x8*)&lfeat[16 + row16][k0 + quad * 8];
#pragma unroll
        for (int ot = 0; ot < 4; ++ot) {
            bf16x8 b = *(const bf16x8*)(WTu + (size_t)(ot * 16 + row16) * FIN + k0 + quad * 8);
            acc[0][ot] = __builtin_amdgcn_mfma_f32_16x16x32_bf16(a0, b, acc[0][ot], 0, 0, 0);
            acc[1][ot] = __builtin_amdgcn_mfma_f32_16x16x32_bf16(a1, b, acc[1][ot], 0, 0, 0);
        }
    }

#pragma unroll
    for (int g = 0; g < 2; ++g)
#pragma unroll
        for (int ot = 0; ot < 4; ++ot) {
            us4 u;
#pragma unroll
            for (int r = 0; r < 4; ++r)
                u[r] = __builtin_bit_cast(unsigned short, (__bf16)acc[g][ot][r]);
            *(us4*)(WhT + (size_t)(h * FOUT + ot * 16 + row16) * NN
                        + tile * 32 + g * 16 + quad * 4) = u;
        }

    float asv[4], adv[4];
#pragma unroll
    for (int ot = 0; ot < 4; ++ot) {
        asv[ot] = a_src[h * FOUT + ot * 16 + row16];
        adv[ot] = a_dst[h * FOUT + ot * 16 + row16];
    }
#pragma unroll
    for (int g = 0; g < 2; ++g)
#pragma unroll
        for (int r = 0; r < 4; ++r) {
            float ss = 0.f, dd = 0.f;
#pragma unroll
            for (int ot = 0; ot < 4; ++ot) {
                ss += acc[g][ot][r] * asv[ot];
                dd += acc[g][ot][r] * adv[ot];
            }
            ss += __shfl_xor(ss, 1); ss += __shfl_xor(ss, 2);
            ss += __shfl_xor(ss, 4); ss += __shfl_xor(ss, 8);
            dd += __shfl_xor(dd, 1); dd += __shfl_xor(dd, 2);
            dd += __shfl_xor(dd, 4); dd += __shfl_xor(dd, 8);
            if (row16 == 0) {
                int n = tile * 32 + g * 16 + quad * 4 + r;
                srcv[h * NN + n] = ss;
                __bf16 e = (__bf16)__expf(dd);
                __bf16 f = (__bf16)__expf(ALPHA * dd);
                Ebf[h * NN + n] = __builtin_bit_cast(unsigned short, e);
                Fbf[h * NN + n] = __builtin_bit_cast(unsigned short, f);
            }
        }
}

// ---------------------------------------------------------------------------
// k_flash: masked softmax attention + ELU. M=128 rows/wave, j-split 8.
// R12 lesson: vmem(46k) + VALU(22k/SIMD) + MFMA(15k) cycles SUM to the
// measured 135k — pipes fully serialized because the score VALU depends on
// the just-issued ev/fv GLOBAL loads (vmcnt wait every iter). Fix: stage the
// E/F tables in LDS once per block (packed E | F<<16, 16 KB); in-loop the
// VALU depends only on ds_read (lgkmcnt ~120cyc) and the only global loads
// left are the 4 B-frags, unneeded until the MFMAs -> ~500 VALU cycles of
// natural latency hiding. vmem/CU: 768 -> ~600 instr.
// Block = 512 thr = 8 waves = 1 head x 8 j-segs (512 j, 16 iters);
// grid dim3(32,8): all 8 same-tile blocks on one XCD. Mask layout/staging
// and combine tree unchanged from R12 (proven).
// ---------------------------------------------------------------------------
__global__ __launch_bounds__(512, 2) void k_flash(
    const unsigned* __restrict__ maskp,
    const float* __restrict__ srcv,
    const unsigned short* __restrict__ Ebf,
    const unsigned short* __restrict__ Fbf,
    const unsigned short* __restrict__ WhT,
    float* __restrict__ out) {
    __shared__ float st[2][128 * 68];        // 69632 B; mask aliases st in-loop
    __shared__ float lds_l[2][128];
    __shared__ unsigned lEF[4096];           // 16 KB: E[j] | F[j]<<16 (one head)

    unsigned* lmask = (unsigned*)&st[0][0];  // [128 rows][132 dwords]

    const int tid   = threadIdx.x;
    const int seg   = tid >> 6;              // 0..7, 512 j each
    const int lane  = tid & 63;
    const int row16 = lane & 15;
    const int quad  = lane >> 4;
    const int shl   = quad * 8;
    const int tile  = blockIdx.x;            // 128 rows
    const int h     = blockIdx.y;

    // ---- stage E/F packed: thread tid covers j = tid*8 .. tid*8+7
    {
        u16x8 ev = *(const u16x8*)(Ebf + h * NN + tid * 8);
        u16x8 fv = *(const u16x8*)(Fbf + h * NN + tid * 8);
        unsigned pk[8];
#pragma unroll
        for (int k = 0; k < 8; ++k)
            pk[k] = (unsigned)ev[k] | ((unsigned)fv[k] << 16);
        *(u32x4*)&lEF[tid * 8]     = *(u32x4*)&pk[0];
        *(u32x4*)&lEF[tid * 8 + 4] = *(u32x4*)&pk[4];
    }

    // ---- stage mask bits for 128 rows (64 row-pair chunks, 1 KB each)
#pragma unroll
    for (int p = 0; p < 8; ++p) {
        int tt = tid + p * 512;
        int c  = tt >> 6;
        int o  = (tt & 63) * 16;
        int4 v = *(const int4*)((const char*)maskp
                                + (size_t)(tile * 64 + c) * 32768 + o);
        int row = c * 2 + (o >> 9);
        int dw  = (o & 511) >> 2;
        *(int4*)&lmask[row * 132 + dw] = v;
    }
    __syncthreads();

    float Es[8], Fs[8];
#pragma unroll
    for (int g = 0; g < 8; ++g) {
        float si = srcv[h * NN + tile * 128 + g * 16 + row16];
        Es[g] = __expf(si);
        Fs[g] = __expf(ALPHA * si);
    }
    const int mbase  = row16 * 132 + seg * 16;   // + g*2112 + t
    const int efbase = seg * 512 + shl;          // + t*32

    const unsigned short* wh = WhT + (size_t)h * FOUT * NN + seg * 512;

    f32x4 acc[8][4] = {};
    float lsum[8]   = {};

#pragma unroll 1
    for (int t = 0; t < 16; ++t) {
        int jj = t * 32 + shl;
        // B-frags: the ONLY global loads in the loop; consumed at the MFMAs
        bf16x8 b[4];
#pragma unroll
        for (int ot = 0; ot < 4; ++ot)
            b[ot] = *(const bf16x8*)(wh + (size_t)(ot * 16 + row16) * NN + jj);

        // E/F from LDS (lgkm only)
        u32x4 d0 = *(const u32x4*)&lEF[efbase + t * 32];
        u32x4 d1 = *(const u32x4*)&lEF[efbase + t * 32 + 4];
        float ef[8], ff[8];
#pragma unroll
        for (int k = 0; k < 4; ++k) {
            ef[k]     = __uint_as_float(d0[k] << 16);
            ff[k]     = __uint_as_float(d0[k] & 0xffff0000u);
            ef[k + 4] = __uint_as_float(d1[k] << 16);
            ff[k + 4] = __uint_as_float(d1[k] & 0xffff0000u);
        }

#pragma unroll
        for (int gp = 0; gp < 4; ++gp) {      // g in pairs: caps live af regs
            const int g0 = gp * 2, g1 = g0 + 1;
            unsigned mb0 = (lmask[mbase + g0 * 2112 + t] >> shl) & 0xffu;
            unsigned mb1 = (lmask[mbase + g1 * 2112 + t] >> shl) & 0xffu;
            union { bf16x8 v8; __hip_bfloat162 h2[4]; } a0u, a1u;
#pragma unroll
            for (int kk = 0; kk < 4; ++kk) {
                const int ka = kk * 2, kb = ka + 1;
                float p0a = ((mb0 >> ka) & 1u) ? fmaxf(ef[ka] * Es[g0], ff[ka] * Fs[g0]) : 0.f;
                float p0b = ((mb0 >> kb) & 1u) ? fmaxf(ef[kb] * Es[g0], ff[kb] * Fs[g0]) : 0.f;
                float p1a = ((mb1 >> ka) & 1u) ? fmaxf(ef[ka] * Es[g1], ff[ka] * Fs[g1]) : 0.f;
                float p1b = ((mb1 >> kb) & 1u) ? fmaxf(ef[kb] * Es[g1], ff[kb] * Fs[g1]) : 0.f;
                lsum[g0] += p0a + p0b;
                lsum[g1] += p1a + p1b;
                a0u.h2[kk] = __float22bfloat162_rn(make_float2(p0a, p0b));
                a1u.h2[kk] = __float22bfloat162_rn(make_float2(p1a, p1b));
            }
#pragma unroll
            for (int ot = 0; ot < 4; ++ot) {
                acc[g0][ot] = __builtin_amdgcn_mfma_f32_16x16x32_bf16(a0u.v8, b[ot], acc[g0][ot], 0, 0, 0);
                acc[g1][ot] = __builtin_amdgcn_mfma_f32_16x16x32_bf16(a1u.v8, b[ot], acc[g1][ot], 0, 0, 0);
            }
        }
    }

    // complete per-row sums across the 4 quads (disjoint k coverage)
#pragma unroll
    for (int g = 0; g < 8; ++g) {
        lsum[g] += __shfl_xor(lsum[g], 16);
        lsum[g] += __shfl_xor(lsum[g], 32);
    }

    __syncthreads();   // mask reads done; st[] may be reused as stash

    auto stash = [&](int buf) {
#pragma unroll
        for (int g = 0; g < 8; ++g)
#pragma unroll
            for (int ot = 0; ot < 4; ++ot)
#pragma unroll
                for (int r = 0; r < 4; ++r)
                    st[buf][(g * 16 + quad * 4 + r) * 68 + ot * 16 + row16] = acc[g][ot][r];
        if (quad == 0)
#pragma unroll
            for (int g = 0; g < 8; ++g)
                lds_l[buf][g * 16 + row16] = lsum[g];
    };
    auto addin = [&](int buf) {
#pragma unroll
        for (int g = 0; g < 8; ++g) {
#pragma unroll
            for (int ot = 0; ot < 4; ++ot)
#pragma unroll
                for (int r = 0; r < 4; ++r)
                    acc[g][ot][r] += st[buf][(g * 16 + quad * 4 + r) * 68 + ot * 16 + row16];
            lsum[g] += lds_l[buf][g * 16 + row16];
        }
    };

    if (seg == 1) stash(0);
    if (seg == 3) stash(1);
    __syncthreads();
    if (seg == 0) addin(0);
    if (seg == 2) addin(1);
    __syncthreads();
    if (seg == 5) stash(0);
    if (seg == 7) stash(1);
    __syncthreads();
    if (seg == 4) addin(0);
    if (seg == 6) addin(1);
    __syncthreads();
    if (seg == 2) stash(0);
    if (seg == 6) stash(1);
    __syncthreads();
    if (seg == 0) addin(0);
    if (seg == 4) addin(1);
    __syncthreads();
    if (seg == 4) stash(0);
    __syncthreads();
    if (seg == 0) {
        addin(0);
        // epilogue: divide by l, ELU, deposit final tile into st[0]
#pragma unroll
        for (int g = 0; g < 8; ++g)
#pragma unroll
            for (int r = 0; r < 4; ++r) {
                int   qr  = quad * 4 + r;
                float l   = __shfl(lsum[g], qr);    // lane qr holds row qr's sum
                float rl  = 1.0f / l;
#pragma unroll
                for (int ot = 0; ot < 4; ++ot) {
                    float v = acc[g][ot][r] * rl;
                    float y = v > 0.f ? v : __expf(v) - 1.f;
                    st[0][(g * 16 + qr) * 68 + ot * 16 + row16] = y;
                }
            }
    }
    __syncthreads();
    // cooperative coalesced store: 2048 float4s by 512 threads
#pragma unroll
    for (int p = 0; p < 4; ++p) {
        int f    = tid + p * 512;
        int row  = f >> 4;
        int col4 = (f & 15) * 4;
        float4 v = *(const float4*)&st[0][row * 68 + col4];
        *(float4*)&out[(size_t)(tile * 128 + row) * (HH * FOUT) + h * FOUT + col4] = v;
    }
}

// ---------------------------------------------------------------------------
extern "C" void kernel_launch(void* const* d_in, const int* in_sizes, int n_in,
                              void* d_out, int out_size, void* d_ws, size_t ws_size,
                              hipStream_t stream) {
    const float* features = (const float*)d_in[0];
    int*         adj      = (int*)d_in[1];     // packed in place by k_prep
    const float* W        = (const float*)d_in[2];
    const float* a_src    = (const float*)d_in[3];
    const float* a_dst    = (const float*)d_in[4];
    float*       out      = (float*)d_out;

    // Workspace: exactly the proven 4.75 MB footprint
    char* ws = (char*)d_ws;
    __hip_bfloat16* WT   = (__hip_bfloat16*)(ws);                             // 512 KB
    unsigned short* WhT  = (unsigned short*)(ws + (512 << 10));               // 4 MB
    float*          srcv = (float*)(ws + (512 << 10) + (4 << 20));            // 128 KB
    unsigned short* Ebf  = (unsigned short*)(ws + (512 << 10) + (4 << 20) + (128 << 10));  // 64 KB
    unsigned short* Fbf  = (unsigned short*)(ws + (512 << 10) + (4 << 20) + (192 << 10));  // 64 KB

    k_transpose_w<<<dim3(64), 256, 0, stream>>>(W, WT);
    k_prep<<<dim3(2048 + 256), 256, 0, stream>>>(adj, features, WT, a_src, a_dst,
                                                 WhT, srcv, Ebf, Fbf);
    k_flash<<<dim3(32, 8), 512, 0, stream>>>((const unsigned*)adj, srcv, Ebf, Fbf,
                                             WhT, out);
}

// Round 14
// 170.428 us; speedup vs baseline: 1.0026x; 1.0026x over previous
//
#include <hip/hip_runtime.h>
#include <hip/hip_bf16.h>

typedef __bf16 bf16x8 __attribute__((ext_vector_type(8)));
typedef float  f32x4  __attribute__((ext_vector_type(4)));
typedef unsigned short u16x8 __attribute__((ext_vector_type(8)));
typedef unsigned short us4   __attribute__((ext_vector_type(4)));

#define HH    8
#define NN    4096
#define FIN   512
#define FOUT  64
#define ALPHA 0.2f

// ---------------------------------------------------------------------------
// k0: W[h][f][o] (fp32) -> WT[h][o][f] (bf16), coalesced via LDS 64x64 tile.
// ---------------------------------------------------------------------------
__global__ __launch_bounds__(256) void k_transpose_w(
    const float* __restrict__ Wsrc, __hip_bfloat16* __restrict__ WT) {
    __shared__ __hip_bfloat16 lt[64][65];
    const int h  = blockIdx.x >> 3;
    const int f0 = (blockIdx.x & 7) * 64;
    const int tid = threadIdx.x;
#pragma unroll
    for (int p = 0; p < 16; ++p) {
        int f = p * 4 + (tid >> 6);
        int o = tid & 63;
        lt[f][o] = __float2bfloat16(Wsrc[((size_t)h * FIN + f0 + f) * FOUT + o]);
    }
    __syncthreads();
#pragma unroll
    for (int p = 0; p < 16; ++p) {
        int o = p * 4 + (tid >> 6);
        int f = tid & 63;
        WT[((size_t)h * FOUT + o) * FIN + f0 + f] = lt[f][o];
    }
}

// ---------------------------------------------------------------------------
// k_prep: FUSED adjacency bit-pack + projection (independent work).
// Blocks [0,2048): in-place pack — block b owns rows 2b,2b+1; first 1 KB of
//   its 32768-B region becomes bits (NOT contiguous across row-pairs).
// Blocks [2048,2304): projection: tile = pb&127 (32 rows), hgroup = pb>>7.
// ---------------------------------------------------------------------------
__global__ __launch_bounds__(256) void k_prep(
    int* __restrict__ adj,
    const float* __restrict__ feat,
    const __hip_bfloat16* __restrict__ WT,
    const float* __restrict__ a_src,
    const float* __restrict__ a_dst,
    unsigned short* __restrict__ WhT,
    float* __restrict__ srcv,
    unsigned short* __restrict__ Ebf, unsigned short* __restrict__ Fbf) {
    __shared__ alignas(16) __hip_bfloat16 lfeat[32][520];

    const int tid = threadIdx.x;

    if (blockIdx.x < 2048) {   // ---- pack path ----
        const size_t base = (size_t)blockIdx.x * 8192;
        unsigned m = 0;
#pragma unroll
        for (int p = 0; p < 8; ++p) {
            int4 v = *(const int4*)(adj + base + tid * 32 + p * 4);
            m |= (unsigned)(v.x > 0) << (p * 4);
            m |= (unsigned)(v.y > 0) << (p * 4 + 1);
            m |= (unsigned)(v.z > 0) << (p * 4 + 2);
            m |= (unsigned)(v.w > 0) << (p * 4 + 3);
        }
        __syncthreads();
        ((unsigned*)adj)[base + tid] = m;
        return;
    }

    // ---- projection path ----
    const int pb   = blockIdx.x - 2048;
    const int tile = pb & 127;            // 32 rows per block
    const int hgy  = pb >> 7;             // 0..1

#pragma unroll
    for (int p = 0; p < 16; ++p) {
        int idx  = p * 256 + tid;
        int row  = idx >> 7;
        int col4 = (idx & 127) * 4;
        float4 f = *(const float4*)(feat + (size_t)(tile * 32 + row) * FIN + col4);
        __hip_bfloat16* dst = &lfeat[row][col4];
        dst[0] = __float2bfloat16(f.x); dst[1] = __float2bfloat16(f.y);
        dst[2] = __float2bfloat16(f.z); dst[3] = __float2bfloat16(f.w);
    }
    __syncthreads();

    const int h     = hgy * 4 + (tid >> 6);
    const int lane  = tid & 63;
    const int row16 = lane & 15;
    const int quad  = lane >> 4;

    const unsigned short* WTu = (const unsigned short*)WT + (size_t)h * FOUT * FIN;

    f32x4 acc[2][4] = {};
    for (int k0 = 0; k0 < FIN; k0 += 32) {
        bf16x8 a0 = *(const bf16x8*)&lfeat[row16][k0 + quad * 8];
        bf16x8 a1 = *(const bf16x8*)&lfeat[16 + row16][k0 + quad * 8];
#pragma unroll
        for (int ot = 0; ot < 4; ++ot) {
            bf16x8 b = *(const bf16x8*)(WTu + (size_t)(ot * 16 + row16) * FIN + k0 + quad * 8);
            acc[0][ot] = __builtin_amdgcn_mfma_f32_16x16x32_bf16(a0, b, acc[0][ot], 0, 0, 0);
            acc[1][ot] = __builtin_amdgcn_mfma_f32_16x16x32_bf16(a1, b, acc[1][ot], 0, 0, 0);
        }
    }

#pragma unroll
    for (int g = 0; g < 2; ++g)
#pragma unroll
        for (int ot = 0; ot < 4; ++ot) {
            us4 u;
#pragma unroll
            for (int r = 0; r < 4; ++r)
                u[r] = __builtin_bit_cast(unsigned short, (__bf16)acc[g][ot][r]);
            *(us4*)(WhT + (size_t)(h * FOUT + ot * 16 + row16) * NN
                        + tile * 32 + g * 16 + quad * 4) = u;
        }

    float asv[4], adv[4];
#pragma unroll
    for (int ot = 0; ot < 4; ++ot) {
        asv[ot] = a_src[h * FOUT + ot * 16 + row16];
        adv[ot] = a_dst[h * FOUT + ot * 16 + row16];
    }
#pragma unroll
    for (int g = 0; g < 2; ++g)
#pragma unroll
        for (int r = 0; r < 4; ++r) {
            float ss = 0.f, dd = 0.f;
#pragma unroll
            for (int ot = 0; ot < 4; ++ot) {
                ss += acc[g][ot][r] * asv[ot];
                dd += acc[g][ot][r] * adv[ot];
            }
            ss += __shfl_xor(ss, 1); ss += __shfl_xor(ss, 2);
            ss += __shfl_xor(ss, 4); ss += __shfl_xor(ss, 8);
            dd += __shfl_xor(dd, 1); dd += __shfl_xor(dd, 2);
            dd += __shfl_xor(dd, 4); dd += __shfl_xor(dd, 8);
            if (row16 == 0) {
                int n = tile * 32 + g * 16 + quad * 4 + r;
                srcv[h * NN + n] = ss;
                __bf16 e = (__bf16)__expf(dd);
                __bf16 f = (__bf16)__expf(ALPHA * dd);
                Ebf[h * NN + n] = __builtin_bit_cast(unsigned short, e);
                Fbf[h * NN + n] = __builtin_bit_cast(unsigned short, f);
            }
        }
}

// ---------------------------------------------------------------------------
// k_flash: masked softmax attention + ELU. M=128 rows/wave, j-split 8.
// = R12 structure (proven 56.4 µs) + distance-1 ev/fv software prefetch.
// R13 lesson: moving ev/fv to LDS split the one batched vmcnt wait into two
// serial wait chains (lgkm for VALU + vmcnt at MFMAs) -> 91 µs. Instead keep
// all 6 loads global but issue ev/fv one iteration early (+4 VGPR): the
// score-VALU's operands arrived a full iteration ago, and b's latency hides
// behind the ~400-cycle VALU block. Regs ~248 <= 256 ((512,2) budget).
// Block = 512 thr = 8 waves = 1 head x 8 j-segs (512 j, 16 iters);
// grid dim3(32,8): all 8 same-tile blocks on one XCD. Mask: 128 rows x 132
// dwords in LDS (67.6 KB) unioned with 2 stash bufs (stride 68).
// p = max(Es*Ed, Fs*Fd) (exp monotone, exact); l accumulated in VALU.
// ---------------------------------------------------------------------------
__global__ __launch_bounds__(512, 2) void k_flash(
    const unsigned* __restrict__ maskp,
    const float* __restrict__ srcv,
    const unsigned short* __restrict__ Ebf,
    const unsigned short* __restrict__ Fbf,
    const unsigned short* __restrict__ WhT,
    float* __restrict__ out) {
    __shared__ float st[2][128 * 68];    // 69632 B; mask aliases st during loop
    __shared__ float lds_l[2][128];

    unsigned* lmask = (unsigned*)&st[0][0];   // [128 rows][132 dwords]

    const int tid   = threadIdx.x;
    const int seg   = tid >> 6;               // 0..7, 512 j each
    const int lane  = tid & 63;
    const int row16 = lane & 15;
    const int quad  = lane >> 4;
    const int shl   = quad * 8;
    const int tile  = blockIdx.x;             // 128 rows
    const int h     = blockIdx.y;

    // ---- stage mask bits for 128 rows (64 row-pair chunks, 1 KB each)
#pragma unroll
    for (int p = 0; p < 8; ++p) {
        int tt = tid + p * 512;
        int c  = tt >> 6;
        int o  = (tt & 63) * 16;
        int4 v = *(const int4*)((const char*)maskp
                                + (size_t)(tile * 64 + c) * 32768 + o);
        int row = c * 2 + (o >> 9);
        int dw  = (o & 511) >> 2;
        *(int4*)&lmask[row * 132 + dw] = v;
    }
    __syncthreads();

    float Es[8], Fs[8];
#pragma unroll
    for (int g = 0; g < 8; ++g) {
        float si = srcv[h * NN + tile * 128 + g * 16 + row16];
        Es[g] = __expf(si);
        Fs[g] = __expf(ALPHA * si);
    }
    const int mbase = row16 * 132 + seg * 16;   // + g*2112 + t

    const unsigned short* Eb = Ebf + h * NN + seg * 512;
    const unsigned short* Fb = Fbf + h * NN + seg * 512;
    const unsigned short* wh = WhT + (size_t)h * FOUT * NN + seg * 512;

    f32x4 acc[8][4] = {};
    float lsum[8]   = {};

    // distance-1 prefetch of ev/fv (iteration t consumes data loaded at t-1)
    u16x8 evA = *(const u16x8*)(Eb + shl);
    u16x8 fvA = *(const u16x8*)(Fb + shl);

#pragma unroll 1
    for (int t = 0; t < 16; ++t) {
        int tn = t + 1 < 16 ? t + 1 : 15;     // clamped tail prefetch
        u16x8 evN = *(const u16x8*)(Eb + tn * 32 + shl);
        u16x8 fvN = *(const u16x8*)(Fb + tn * 32 + shl);

        int jj = t * 32 + shl;
        bf16x8 b[4];
#pragma unroll
        for (int ot = 0; ot < 4; ++ot)
            b[ot] = *(const bf16x8*)(wh + (size_t)(ot * 16 + row16) * NN + jj);

        float ef[8], ff[8];
#pragma unroll
        for (int k = 0; k < 8; ++k) {
            ef[k] = __uint_as_float((unsigned)evA[k] << 16);
            ff[k] = __uint_as_float((unsigned)fvA[k] << 16);
        }

#pragma unroll
        for (int gp = 0; gp < 4; ++gp) {      // g in pairs: caps live af regs
            const int g0 = gp * 2, g1 = g0 + 1;
            unsigned mb0 = (lmask[mbase + g0 * 2112 + t] >> shl) & 0xffu;
            unsigned mb1 = (lmask[mbase + g1 * 2112 + t] >> shl) & 0xffu;
            union { bf16x8 v8; __hip_bfloat162 h2[4]; } a0u, a1u;
#pragma unroll
            for (int kk = 0; kk < 4; ++kk) {
                const int ka = kk * 2, kb = ka + 1;
                float p0a = ((mb0 >> ka) & 1u) ? fmaxf(ef[ka] * Es[g0], ff[ka] * Fs[g0]) : 0.f;
                float p0b = ((mb0 >> kb) & 1u) ? fmaxf(ef[kb] * Es[g0], ff[kb] * Fs[g0]) : 0.f;
                float p1a = ((mb1 >> ka) & 1u) ? fmaxf(ef[ka] * Es[g1], ff[ka] * Fs[g1]) : 0.f;
                float p1b = ((mb1 >> kb) & 1u) ? fmaxf(ef[kb] * Es[g1], ff[kb] * Fs[g1]) : 0.f;
                lsum[g0] += p0a + p0b;
                lsum[g1] += p1a + p1b;
                a0u.h2[kk] = __float22bfloat162_rn(make_float2(p0a, p0b));
                a1u.h2[kk] = __float22bfloat162_rn(make_float2(p1a, p1b));
            }
#pragma unroll
            for (int ot = 0; ot < 4; ++ot) {
                acc[g0][ot] = __builtin_amdgcn_mfma_f32_16x16x32_bf16(a0u.v8, b[ot], acc[g0][ot], 0, 0, 0);
                acc[g1][ot] = __builtin_amdgcn_mfma_f32_16x16x32_bf16(a1u.v8, b[ot], acc[g1][ot], 0, 0, 0);
            }
        }
        evA = evN; fvA = fvN;
    }

    // complete per-row sums across the 4 quads (disjoint k coverage)
#pragma unroll
    for (int g = 0; g < 8; ++g) {
        lsum[g] += __shfl_xor(lsum[g], 16);
        lsum[g] += __shfl_xor(lsum[g], 32);
    }

    __syncthreads();   // mask reads done; st[] may be reused as stash

    auto stash = [&](int buf) {
#pragma unroll
        for (int g = 0; g < 8; ++g)
#pragma unroll
            for (int ot = 0; ot < 4; ++ot)
#pragma unroll
                for (int r = 0; r < 4; ++r)
                    st[buf][(g * 16 + quad * 4 + r) * 68 + ot * 16 + row16] = acc[g][ot][r];
        if (quad == 0)
#pragma unroll
            for (int g = 0; g < 8; ++g)
                lds_l[buf][g * 16 + row16] = lsum[g];
    };
    auto addin = [&](int buf) {
#pragma unroll
        for (int g = 0; g < 8; ++g) {
#pragma unroll
            for (int ot = 0; ot < 4; ++ot)
#pragma unroll
                for (int r = 0; r < 4; ++r)
                    acc[g][ot][r] += st[buf][(g * 16 + quad * 4 + r) * 68 + ot * 16 + row16];
            lsum[g] += lds_l[buf][g * 16 + row16];
        }
    };

    if (seg == 1) stash(0);
    if (seg == 3) stash(1);
    __syncthreads();
    if (seg == 0) addin(0);
    if (seg == 2) addin(1);
    __syncthreads();
    if (seg == 5) stash(0);
    if (seg == 7) stash(1);
    __syncthreads();
    if (seg == 4) addin(0);
    if (seg == 6) addin(1);
    __syncthreads();
    if (seg == 2) stash(0);
    if (seg == 6) stash(1);
    __syncthreads();
    if (seg == 0) addin(0);
    if (seg == 4) addin(1);
    __syncthreads();
    if (seg == 4) stash(0);
    __syncthreads();
    if (seg == 0) {
        addin(0);
        // epilogue: divide by l, ELU, deposit final tile into st[0]
#pragma unroll
        for (int g = 0; g < 8; ++g)
#pragma unroll
            for (int r = 0; r < 4; ++r) {
                int   qr  = quad * 4 + r;
                float l   = __shfl(lsum[g], qr);    // lane qr holds row qr's sum
                float rl  = 1.0f / l;
#pragma unroll
                for (int ot = 0; ot < 4; ++ot) {
                    float v = acc[g][ot][r] * rl;
                    float y = v > 0.f ? v : __expf(v) - 1.f;
                    st[0][(g * 16 + qr) * 68 + ot * 16 + row16] = y;
                }
            }
    }
    __syncthreads();
    // cooperative coalesced store: 2048 float4s by 512 threads
#pragma unroll
    for (int p = 0; p < 4; ++p) {
        int f    = tid + p * 512;
        int row  = f >> 4;
        int col4 = (f & 15) * 4;
        float4 v = *(const float4*)&st[0][row * 68 + col4];
        *(float4*)&out[(size_t)(tile * 128 + row) * (HH * FOUT) + h * FOUT + col4] = v;
    }
}

// ---------------------------------------------------------------------------
extern "C" void kernel_launch(void* const* d_in, const int* in_sizes, int n_in,
                              void* d_out, int out_size, void* d_ws, size_t ws_size,
                              hipStream_t stream) {
    const float* features = (const float*)d_in[0];
    int*         adj      = (int*)d_in[1];     // packed in place by k_prep
    const float* W        = (const float*)d_in[2];
    const float* a_src    = (const float*)d_in[3];
    const float* a_dst    = (const float*)d_in[4];
    float*       out      = (float*)d_out;

    // Workspace: exactly the proven 4.75 MB footprint
    char* ws = (char*)d_ws;
    __hip_bfloat16* WT   = (__hip_bfloat16*)(ws);                             // 512 KB
    unsigned short* WhT  = (unsigned short*)(ws + (512 << 10));               // 4 MB
    float*          srcv = (float*)(ws + (512 << 10) + (4 << 20));            // 128 KB
    unsigned short* Ebf  = (unsigned short*)(ws + (512 << 10) + (4 << 20) + (128 << 10));  // 64 KB
    unsigned short* Fbf  = (unsigned short*)(ws + (512 << 10) + (4 << 20) + (192 << 10));  // 64 KB

    k_transpose_w<<<dim3(64), 256, 0, stream>>>(W, WT);
    k_prep<<<dim3(2048 + 256), 256, 0, stream>>>(adj, features, WT, a_src, a_dst,
                                                 WhT, srcv, Ebf, Fbf);
    k_flash<<<dim3(32, 8), 512, 0, stream>>>((const unsigned*)adj, srcv, Ebf, Fbf,
                                             WhT, out);
}